// Round 5
// baseline (164.696 us; speedup 1.0000x reference)
//
#include <hip/hip_runtime.h>
#include <math.h>

#define EPS_F 1e-8f

typedef __attribute__((ext_vector_type(8))) short bf16x8;
typedef __attribute__((ext_vector_type(4))) float f32x4;

__device__ inline short f2bf(float f) {
    union { float f; unsigned u; } v; v.f = f;
    unsigned r = (v.u + 0x7fffu + ((v.u >> 16) & 1u)) >> 16;
    return (short)r;
}

// ---------------------------------------------------------------------------
// Kernel 1: per-batch small math (round-3 version, passed) + NEW: convert
// Wf (256x256 fp32, cols 0..255 of projW) to bf16 in MFMA-fragment layout
// ws_A[k>>3][m][k&7], so the GEMM can load A fragments straight from global
// with one dwordx4 per lane and no LDS/barrier.
// Block b converts k in [b*16, b*16+16); thread t = row m.
// ---------------------------------------------------------------------------
__global__ __launch_bounds__(256) void prelim_kernel(
    const float* __restrict__ mu_prior,   // (16,128,32)
    const float* __restrict__ ls_prior,   // (16,128,32)
    const float* __restrict__ pi_prior,   // (16,32)
    const float* __restrict__ mu_post,    // (16,128)
    const float* __restrict__ ls_post,    // (16,128)
    const float* __restrict__ noise_c,    // (16,128)
    const float* __restrict__ noise_z,    // (16,128)
    const float* __restrict__ projW,      // (256,384)
    const float* __restrict__ projb,      // (256,)
    float* __restrict__ ws_bias,          // (16,256)
    short* __restrict__ ws_A,             // (32,256,8) bf16 fragment-major
    float* __restrict__ kld_out)          // &out[16777216], pre-zeroed
{
    const int b = blockIdx.x;
    const int t = threadIdx.x;  // 0..255

    // --- Wf -> bf16 fragment-major conversion (independent of the rest) ---
    {
        const float* wrow = projW + t * 384 + b * 16;
        bf16x8 w0, w1;
#pragma unroll
        for (int j = 0; j < 8; ++j) w0[j] = f2bf(wrow[j]);
#pragma unroll
        for (int j = 0; j < 8; ++j) w1[j] = f2bf(wrow[8 + j]);
        *(bf16x8*)&ws_A[(b * 2 + 0) * 2048 + t * 8] = w0;
        *(bf16x8*)&ws_A[(b * 2 + 1) * 2048 + t * 8] = w1;
    }

    __shared__ float s_zpost[128];
    __shared__ float s_zc[128];
    __shared__ float s_mu[128];
    __shared__ float s_e2[128];
    __shared__ float s_lsp[128];
    __shared__ float s_kstd[128];
    __shared__ float s_p1[8][32];
    __shared__ float s_p2[8][32];

    if (t < 128) {
        const float mu = mu_post[b * 128 + t];
        const float ls = ls_post[b * 128 + t];
        const float el = __expf(ls);
        s_zpost[t] = mu + el * noise_c[b * 128 + t];
        s_zc[t]    = mu + (el + EPS_F) * noise_z[b * 128 + t];
        s_mu[t]    = mu;
        s_e2[t]    = el * el;
        s_lsp[t]   = ls;
        s_kstd[t]  = -ls + 0.5f * (el * el + mu * mu) - 0.5f;
    }
    __syncthreads();

    {
        const int c = t & 31;
        const int g = t >> 5;
        const float* mpB = mu_prior + b * 4096;
        const float* lpB = ls_prior + b * 4096;
        float lp = 0.f, kg = 0.f;
#pragma unroll 4
        for (int j = 0; j < 16; ++j) {
            const int d = g * 16 + j;
            const float mpr  = mpB[d * 32 + c];
            const float lpr  = lpB[d * 32 + c];
            const float inv2 = 0.5f * __expf(-2.f * lpr);
            const float zd   = s_zpost[d] - mpr;
            lp += -lpr - 0.91893853320467274f - zd * zd * inv2;
            const float dm   = s_mu[d] - mpr;
            const float e2pr = __expf(2.f * lpr);
            kg += lpr - s_lsp[d]
                + (s_e2[d] + dm * dm) * __builtin_amdgcn_rcpf(2.f * e2pr + EPS_F)
                - 0.5f;
        }
        s_p1[g][c] = lp;
        s_p2[g][c] = kg;
    }
    __syncthreads();

    if (t < 64) {
        const int c = t & 31;
        float lp = 0.f, kg = 0.f;
#pragma unroll
        for (int g = 0; g < 8; ++g) { lp += s_p1[g][c]; kg += s_p2[g][c]; }
        float ks = s_kstd[c] + s_kstd[c + 32] + s_kstd[c + 64] + s_kstd[c + 96];
        const float pp = pi_prior[b * 32 + c];

        float m = lp;
#pragma unroll
        for (int o = 16; o; o >>= 1) m = fmaxf(m, __shfl_xor(m, o, 32));
        const float e = __expf(lp - m);
        float den = e;
#pragma unroll
        for (int o = 16; o; o >>= 1) den += __shfl_xor(den, o, 32);
        const float pi = e * __builtin_amdgcn_rcpf(den);
        float tot = pi * kg + pi * (__logf(pi + EPS_F) - __logf(pp + EPS_F));
#pragma unroll
        for (int o = 16; o; o >>= 1) tot += __shfl_xor(tot, o, 32);
#pragma unroll
        for (int o = 16; o; o >>= 1) ks += __shfl_xor(ks, o, 32);
        if (t == 0) atomicAdd(kld_out, (tot + ks) * 0.0625f);
    }

    {
        const int o = t;
        const float4* wrow = (const float4*)(projW + o * 384 + 256);
        float sum = projb[o];
#pragma unroll 8
        for (int j = 0; j < 32; ++j) {
            const float4 w = wrow[j];
            sum += s_zc[4 * j + 0] * w.x + s_zc[4 * j + 1] * w.y +
                   s_zc[4 * j + 2] * w.z + s_zc[4 * j + 3] * w.w;
        }
        ws_bias[b * 256 + o] = sum;
    }
}

// ---------------------------------------------------------------------------
// Kernel 2: bf16 MFMA GEMM, BARRIER-FREE K-loop.
// R2-R4 all pinned at ~44 us: the 2-barrier K-loop drains vmcnt(0) at the
// pack step every chunk, so all waves eat global latency in lockstep.
// Here: A fragments load directly from ws_A (pre-converted, fragment-major,
// L2-hot); B fragments load directly from f_curr into registers (32 dword
// loads/wave/chunk, double-buffered one chunk ahead), packed to bf16 at
// consume time. No LDS in the K-loop, no __syncthreads -> waves slip freely.
// Tile 128x128, 4 waves (2M x 2N), wave tile 64x64 = 4x4 of 16x16x32.
// ---------------------------------------------------------------------------
__global__ __launch_bounds__(256) void gemm_kernel(
    const float* __restrict__ F,     // (16,256,4096) fp32
    const short* __restrict__ wsA,   // (32,256,8) bf16 fragment-major
    const float* __restrict__ bias,  // (16,256)
    float* __restrict__ O)           // (16,256,4096)
{
    const int nT = blockIdx.x;  // 0..31  (HW tiles of 128)
    const int oT = blockIdx.y;  // 0..1   (O tiles of 128)
    const int b  = blockIdx.z;  // 0..15

    __shared__ float s_bias[128];

    const int tid  = threadIdx.x;
    const int lane = tid & 63;
    const int wave = tid >> 6;  // 0..3
    const int wm = wave & 1;
    const int wn = wave >> 1;
    const int kg = lane >> 4;   // 0..3
    const int lm = lane & 15;

    if (tid < 128) s_bias[tid] = bias[b * 256 + oT * 128 + tid];

    // A fragment base: ws_A[(kc*4+kg)][oT*128 + wm*64 + mt*16 + lm][0..7]
    const short* aBase = wsA + (size_t)kg * 2048 + (oT * 128 + wm * 64 + lm) * 8;
    // B lane base: F[b][kg*8 + j][nT*128 + wn*64 + nt*16 + lm]
    const float* bBase = F + (size_t)b * 1048576 + (size_t)(kg * 8) * 4096
                       + nT * 128 + wn * 64 + lm;

    f32x4 acc[4][4];
#pragma unroll
    for (int i = 0; i < 4; ++i)
#pragma unroll
        for (int j = 0; j < 4; ++j) acc[i][j] = (f32x4){0.f, 0.f, 0.f, 0.f};

    float Bbuf[2][32];  // [buf][nt*8+j]

    // preload chunk 0 B
#pragma unroll
    for (int nt = 0; nt < 4; ++nt)
#pragma unroll
        for (int j = 0; j < 8; ++j)
            Bbuf[0][nt * 8 + j] = bBase[(size_t)j * 4096 + nt * 16];

#pragma unroll
    for (int kc = 0; kc < 8; ++kc) {
        const int cur = kc & 1, nxt = cur ^ 1;

        // issue next chunk's B loads (latency hidden behind pack+MFMA)
        if (kc < 7) {
            const float* bp = bBase + (size_t)(kc + 1) * 32 * 4096;
#pragma unroll
            for (int nt = 0; nt < 4; ++nt)
#pragma unroll
                for (int j = 0; j < 8; ++j)
                    Bbuf[nxt][nt * 8 + j] = bp[(size_t)j * 4096 + nt * 16];
        }

        // A fragments for this chunk (L2-hot, short dependency distance)
        bf16x8 aF[4];
#pragma unroll
        for (int mt = 0; mt < 4; ++mt)
            aF[mt] = *(const bf16x8*)(aBase + (size_t)kc * 8192 + mt * 128);

        // pack current B to bf16
        bf16x8 bF[4];
#pragma unroll
        for (int nt = 0; nt < 4; ++nt)
#pragma unroll
            for (int j = 0; j < 8; ++j)
                bF[nt][j] = f2bf(Bbuf[cur][nt * 8 + j]);

#pragma unroll
        for (int mt = 0; mt < 4; ++mt)
#pragma unroll
            for (int nt = 0; nt < 4; ++nt)
                acc[mt][nt] = __builtin_amdgcn_mfma_f32_16x16x32_bf16(
                    aF[mt], bF[nt], acc[mt][nt], 0, 0, 0);
    }

    __syncthreads();  // s_bias ready (only barrier in the kernel)

    // epilogue: + bias.  C/D: col = lane&15, row = (lane>>4)*4+reg
    float* Ob = O + (size_t)b * 1048576 + (size_t)oT * 128 * 4096;
    const int rbase = wm * 64 + kg * 4;
    const int cbase = nT * 128 + wn * 64 + lm;
#pragma unroll
    for (int mt = 0; mt < 4; ++mt) {
#pragma unroll
        for (int r = 0; r < 4; ++r) {
            const int row = rbase + mt * 16 + r;
            const float bb = s_bias[row];
            float* orow = Ob + (size_t)row * 4096 + cbase;
#pragma unroll
            for (int nt = 0; nt < 4; ++nt)
                orow[nt * 16] = acc[mt][nt][r] + bb;
        }
    }
}

extern "C" void kernel_launch(void* const* d_in, const int* in_sizes, int n_in,
                              void* d_out, int out_size, void* d_ws, size_t ws_size,
                              hipStream_t stream) {
    const float* f_curr   = (const float*)d_in[0];  // (16,256,64,64)
    const float* mu_prior = (const float*)d_in[1];  // (16,128,32)
    const float* ls_prior = (const float*)d_in[2];  // (16,128,32)
    const float* pi_prior = (const float*)d_in[3];  // (16,32)
    const float* mu_post  = (const float*)d_in[4];  // (16,128)
    const float* ls_post  = (const float*)d_in[5];  // (16,128)
    const float* noise_c  = (const float*)d_in[6];  // (16,128)
    const float* noise_z  = (const float*)d_in[7];  // (16,128)
    const float* projW    = (const float*)d_in[8];  // (256,384)
    const float* projb    = (const float*)d_in[9];  // (256,)

    float* out = (float*)d_out;          // 16*256*64*64 f_out + 1 kld
    float* ws  = (float*)d_ws;
    float* ws_bias = ws;                 // 16*256 floats (16 KB)
    short* ws_A    = (short*)(ws + 4096);// 32*256*8 bf16 (128 KB)

    float* kld_out = out + 16777216;
    hipMemsetAsync(kld_out, 0, sizeof(float), stream);

    prelim_kernel<<<16, 256, 0, stream>>>(mu_prior, ls_prior, pi_prior, mu_post,
                                          ls_post, noise_c, noise_z, projW, projb,
                                          ws_bias, ws_A, kld_out);
    gemm_kernel<<<dim3(32, 2, 16), 256, 0, stream>>>(f_curr, ws_A, ws_bias, out);
}

// Round 6
// 146.237 us; speedup vs baseline: 1.1262x; 1.1262x over previous
//
#include <hip/hip_runtime.h>
#include <math.h>

#define EPS_F 1e-8f

typedef __attribute__((ext_vector_type(8))) short bf16x8;
typedef __attribute__((ext_vector_type(4))) float f32x4;

__device__ inline short f2bf(float f) {
    union { float f; unsigned u; } v; v.f = f;
    unsigned r = (v.u + 0x7fffu + ((v.u >> 16) & 1u)) >> 16;
    return (short)r;
}

// ---------------------------------------------------------------------------
// Kernel 1: per-batch small math + Wf -> bf16 fragment-major ws_A
// (unchanged from round 5 — both parts verified passing).
// ---------------------------------------------------------------------------
__global__ __launch_bounds__(256) void prelim_kernel(
    const float* __restrict__ mu_prior,   // (16,128,32)
    const float* __restrict__ ls_prior,   // (16,128,32)
    const float* __restrict__ pi_prior,   // (16,32)
    const float* __restrict__ mu_post,    // (16,128)
    const float* __restrict__ ls_post,    // (16,128)
    const float* __restrict__ noise_c,    // (16,128)
    const float* __restrict__ noise_z,    // (16,128)
    const float* __restrict__ projW,      // (256,384)
    const float* __restrict__ projb,      // (256,)
    float* __restrict__ ws_bias,          // (16,256)
    short* __restrict__ ws_A,             // (32,256,8) bf16 fragment-major
    float* __restrict__ kld_out)          // &out[16777216], pre-zeroed
{
    const int b = blockIdx.x;
    const int t = threadIdx.x;  // 0..255

    {
        const float* wrow = projW + t * 384 + b * 16;
        bf16x8 w0, w1;
#pragma unroll
        for (int j = 0; j < 8; ++j) w0[j] = f2bf(wrow[j]);
#pragma unroll
        for (int j = 0; j < 8; ++j) w1[j] = f2bf(wrow[8 + j]);
        *(bf16x8*)&ws_A[(b * 2 + 0) * 2048 + t * 8] = w0;
        *(bf16x8*)&ws_A[(b * 2 + 1) * 2048 + t * 8] = w1;
    }

    __shared__ float s_zpost[128];
    __shared__ float s_zc[128];
    __shared__ float s_mu[128];
    __shared__ float s_e2[128];
    __shared__ float s_lsp[128];
    __shared__ float s_kstd[128];
    __shared__ float s_p1[8][32];
    __shared__ float s_p2[8][32];

    if (t < 128) {
        const float mu = mu_post[b * 128 + t];
        const float ls = ls_post[b * 128 + t];
        const float el = __expf(ls);
        s_zpost[t] = mu + el * noise_c[b * 128 + t];
        s_zc[t]    = mu + (el + EPS_F) * noise_z[b * 128 + t];
        s_mu[t]    = mu;
        s_e2[t]    = el * el;
        s_lsp[t]   = ls;
        s_kstd[t]  = -ls + 0.5f * (el * el + mu * mu) - 0.5f;
    }
    __syncthreads();

    {
        const int c = t & 31;
        const int g = t >> 5;
        const float* mpB = mu_prior + b * 4096;
        const float* lpB = ls_prior + b * 4096;
        float lp = 0.f, kg = 0.f;
#pragma unroll 4
        for (int j = 0; j < 16; ++j) {
            const int d = g * 16 + j;
            const float mpr  = mpB[d * 32 + c];
            const float lpr  = lpB[d * 32 + c];
            const float inv2 = 0.5f * __expf(-2.f * lpr);
            const float zd   = s_zpost[d] - mpr;
            lp += -lpr - 0.91893853320467274f - zd * zd * inv2;
            const float dm   = s_mu[d] - mpr;
            const float e2pr = __expf(2.f * lpr);
            kg += lpr - s_lsp[d]
                + (s_e2[d] + dm * dm) * __builtin_amdgcn_rcpf(2.f * e2pr + EPS_F)
                - 0.5f;
        }
        s_p1[g][c] = lp;
        s_p2[g][c] = kg;
    }
    __syncthreads();

    if (t < 64) {
        const int c = t & 31;
        float lp = 0.f, kg = 0.f;
#pragma unroll
        for (int g = 0; g < 8; ++g) { lp += s_p1[g][c]; kg += s_p2[g][c]; }
        float ks = s_kstd[c] + s_kstd[c + 32] + s_kstd[c + 64] + s_kstd[c + 96];
        const float pp = pi_prior[b * 32 + c];

        float m = lp;
#pragma unroll
        for (int o = 16; o; o >>= 1) m = fmaxf(m, __shfl_xor(m, o, 32));
        const float e = __expf(lp - m);
        float den = e;
#pragma unroll
        for (int o = 16; o; o >>= 1) den += __shfl_xor(den, o, 32);
        const float pi = e * __builtin_amdgcn_rcpf(den);
        float tot = pi * kg + pi * (__logf(pi + EPS_F) - __logf(pp + EPS_F));
#pragma unroll
        for (int o = 16; o; o >>= 1) tot += __shfl_xor(tot, o, 32);
#pragma unroll
        for (int o = 16; o; o >>= 1) ks += __shfl_xor(ks, o, 32);
        if (t == 0) atomicAdd(kld_out, (tot + ks) * 0.0625f);
    }

    {
        const int o = t;
        const float4* wrow = (const float4*)(projW + o * 384 + 256);
        float sum = projb[o];
#pragma unroll 8
        for (int j = 0; j < 32; ++j) {
            const float4 w = wrow[j];
            sum += s_zc[4 * j + 0] * w.x + s_zc[4 * j + 1] * w.y +
                   s_zc[4 * j + 2] * w.z + s_zc[4 * j + 3] * w.w;
        }
        ws_bias[b * 256 + o] = sum;
    }
}

// ---------------------------------------------------------------------------
// Kernel 2: bf16 MFMA GEMM — SINGLE-BARRIER structure.
// R2-R4 (barrier per chunk) and R5 (no barrier, thin prefetch) both expose
// global latency once per K-chunk (~44 / ~54 us). K=256 is small: stage the
// ENTIRE K-range of the B tile to LDS in one burst (16 dwordx4 per thread,
// one latency window, VMEM-pipelined), ONE __syncthreads, then an 8-chunk
// all-LDS + MFMA loop with no barriers and no global B traffic.
// BM=256 (full O, f_curr read exactly once), BN=64, 256 thr = 4 waves,
// wave tile 64x64 = 4x4 MFMA 16x16x32. B-LDS 32 KB bf16 -> 4 blocks/CU.
// A fragments stream from ws_A (bf16 fragment-major, L2-hot).
// ---------------------------------------------------------------------------
__global__ __launch_bounds__(256) void gemm_kernel(
    const float* __restrict__ F,     // (16,256,4096) fp32
    const short* __restrict__ wsA,   // (32,256,8) bf16 fragment-major
    const float* __restrict__ bias,  // (16,256)
    float* __restrict__ O)           // (16,256,4096)
{
    const int nT = blockIdx.x;  // 0..63  (HW tiles of 64)
    const int b  = blockIdx.y;  // 0..15

    __shared__ short Bl[32][64][8];  // [k>>3][n][k&7]  32 KB
    __shared__ float s_bias[256];

    const int tid  = threadIdx.x;
    const int lane = tid & 63;
    const int wave = tid >> 6;  // 0..3  (M offset wave*64)
    const int kg   = lane >> 4; // 0..3
    const int lm   = lane & 15;

    s_bias[tid] = bias[b * 256 + tid];

    // ---- stage full B tile: thread covers 16 k's x 4 n's ----
    const int sn4 = (tid & 15) * 4;      // n offset, 4 cols
    const int skb = (tid >> 4) * 16;     // k base, 16 rows
    const float* fp = F + (size_t)b * 1048576 + (size_t)skb * 4096
                    + nT * 64 + sn4;

    float4 ld[16];
#pragma unroll
    for (int i = 0; i < 16; ++i)
        ld[i] = *(const float4*)(fp + (size_t)i * 4096);

#pragma unroll
    for (int h = 0; h < 2; ++h) {        // two kg groups of 8 k's
        const int kgi = (skb >> 3) + h;
#pragma unroll
        for (int c = 0; c < 4; ++c) {    // 4 n's
            bf16x8 v;
#pragma unroll
            for (int j = 0; j < 8; ++j) {
                const float4 q = ld[h * 8 + j];
                v[j] = f2bf(c == 0 ? q.x : c == 1 ? q.y : c == 2 ? q.z : q.w);
            }
            *(bf16x8*)&Bl[kgi][sn4 + c][0] = v;
        }
    }
    __syncthreads();  // the ONLY barrier

    // ---- K loop: all-LDS B, L2 A, no barriers ----
    const short* aBase = wsA + (size_t)kg * 2048 + (wave * 64 + lm) * 8;

    f32x4 acc[4][4];
#pragma unroll
    for (int i = 0; i < 4; ++i)
#pragma unroll
        for (int j = 0; j < 4; ++j) acc[i][j] = (f32x4){0.f, 0.f, 0.f, 0.f};

#pragma unroll
    for (int kc = 0; kc < 8; ++kc) {
        bf16x8 aF[4], bF[4];
#pragma unroll
        for (int mt = 0; mt < 4; ++mt)
            aF[mt] = *(const bf16x8*)(aBase + (size_t)kc * 8192 + mt * 128);
#pragma unroll
        for (int nt = 0; nt < 4; ++nt)
            bF[nt] = *(const bf16x8*)&Bl[kc * 4 + kg][nt * 16 + lm][0];

#pragma unroll
        for (int mt = 0; mt < 4; ++mt)
#pragma unroll
            for (int nt = 0; nt < 4; ++nt)
                acc[mt][nt] = __builtin_amdgcn_mfma_f32_16x16x32_bf16(
                    aF[mt], bF[nt], acc[mt][nt], 0, 0, 0);
    }

    // ---- epilogue: + bias.  C/D: col = lane&15, row = (lane>>4)*4+reg ----
    float* Ob = O + (size_t)b * 1048576 + nT * 64;
    const int rbase = wave * 64 + kg * 4;
    const int cbase = lm;
#pragma unroll
    for (int mt = 0; mt < 4; ++mt) {
#pragma unroll
        for (int r = 0; r < 4; ++r) {
            const int row = rbase + mt * 16 + r;
            const float bb = s_bias[row];
            float* orow = Ob + (size_t)row * 4096 + cbase;
#pragma unroll
            for (int nt = 0; nt < 4; ++nt)
                orow[nt * 16] = acc[mt][nt][r] + bb;
        }
    }
}

extern "C" void kernel_launch(void* const* d_in, const int* in_sizes, int n_in,
                              void* d_out, int out_size, void* d_ws, size_t ws_size,
                              hipStream_t stream) {
    const float* f_curr   = (const float*)d_in[0];  // (16,256,64,64)
    const float* mu_prior = (const float*)d_in[1];  // (16,128,32)
    const float* ls_prior = (const float*)d_in[2];  // (16,128,32)
    const float* pi_prior = (const float*)d_in[3];  // (16,32)
    const float* mu_post  = (const float*)d_in[4];  // (16,128)
    const float* ls_post  = (const float*)d_in[5];  // (16,128)
    const float* noise_c  = (const float*)d_in[6];  // (16,128)
    const float* noise_z  = (const float*)d_in[7];  // (16,128)
    const float* projW    = (const float*)d_in[8];  // (256,384)
    const float* projb    = (const float*)d_in[9];  // (256,)

    float* out = (float*)d_out;          // 16*256*64*64 f_out + 1 kld
    float* ws  = (float*)d_ws;
    float* ws_bias = ws;                 // 16*256 floats (16 KB)
    short* ws_A    = (short*)(ws + 4096);// 32*256*8 bf16 (128 KB)

    float* kld_out = out + 16777216;
    hipMemsetAsync(kld_out, 0, sizeof(float), stream);

    prelim_kernel<<<16, 256, 0, stream>>>(mu_prior, ls_prior, pi_prior, mu_post,
                                          ls_post, noise_c, noise_z, projW, projb,
                                          ws_bias, ws_A, kld_out);
    gemm_kernel<<<dim3(64, 16), 256, 0, stream>>>(f_curr, ws_A, ws_bias, out);
}